// Round 1
// baseline (106.908 us; speedup 1.0000x reference)
//
#include <hip/hip_runtime.h>
#include <math.h>

#define BB 16
#define NBB 512
#define BSS 128
#define KK 32
#define NBLK (BB*NBB)        // 8192 query blocks
#define STATS_GRID 1024      // 1,048,576 elems / (256 thr * 4 elem)

// W (float) layout (all qb-indexed arrays packed for kernel-2 access pattern):
//   [0     ..16384)   VC   float2 per qblock: {Svp (sum vld*p), Cv (count vld)}
//   [16384 ..49152)   SU   float4 per qblock: {Sup, Sup2, Cu, 0}
//   [49152 ..65536)   BC   float2 per qblock: {bceSum, bceCnt}
//   [65536 ..65570)   P    accumulators: [16]x{loss,nunc} then bs(32), bc(33)
//   [65570]           ticket (int)

#define VC_OFF 0
#define SU_OFF 16384
#define BC_OFF 49152
#define P_OFF  65536
#define TICKET_OFF 65570

// Kernel 1: per-query-block stats, vectorized. 1024 blocks x 256 threads;
// each thread handles 4 contiguous elements (float4), so each 32-lane group
// covers exactly one 128-element query block. Mask encoding (1-byte bool vs
// 4-byte word) detected per block by sampling 1024 bytes at offset%4==1 in
// the first 4KB of sup (nonzero there only possible for byte-packed bools;
// ~10% true density => miss prob 0.9^1024 ~ 1e-47).
__global__ __launch_bounds__(256) void stats_kernel(
    const float* __restrict__ logits, const float* __restrict__ targets,
    const unsigned char* __restrict__ sup_b, const unsigned char* __restrict__ ign_b,
    float* __restrict__ W)
{
    const int t = threadIdx.x;
    __shared__ int s_mode;
    if (t == 0) s_mode = 0;
    __syncthreads();
    int local = 0;
    #pragma unroll
    for (int r = 0; r < 4; ++r) {
        if (sup_b[4 * (t + 256 * r) + 1] != 0) local = 1;
    }
    if (local) atomicOr(&s_mode, 1);
    __syncthreads();
    const bool byteMode = (s_mode != 0);

    const int gid = blockIdx.x * 256 + t;          // float4 index
    const float4 x4 = ((const float4*)logits)[gid];
    const float4 t4 = ((const float4*)targets)[gid];
    bool s[4], g[4];
    if (byteMode) {
        const unsigned int sm = ((const unsigned int*)sup_b)[gid];
        const unsigned int gm = ((const unsigned int*)ign_b)[gid];
        #pragma unroll
        for (int j = 0; j < 4; ++j) {
            s[j] = ((sm >> (8 * j)) & 0xffu) != 0;
            g[j] = ((gm >> (8 * j)) & 0xffu) != 0;
        }
    } else {
        const int4 sm = ((const int4*)sup_b)[gid];
        const int4 gm = ((const int4*)ign_b)[gid];
        s[0] = sm.x != 0; s[1] = sm.y != 0; s[2] = sm.z != 0; s[3] = sm.w != 0;
        g[0] = gm.x != 0; g[1] = gm.y != 0; g[2] = gm.z != 0; g[3] = gm.w != 0;
    }
    const float xs[4] = {x4.x, x4.y, x4.z, x4.w};
    const float ts[4] = {t4.x, t4.y, t4.z, t4.w};

    float svp = 0.f, cv = 0.f, su = 0.f, su2 = 0.f, cu = 0.f, bs = 0.f, bc = 0.f;
    #pragma unroll
    for (int j = 0; j < 4; ++j) {
        const float x = xs[j];
        const float p = 1.0f / (1.0f + expf(-x));
        if (s[j]) {
            bs += fmaxf(x, 0.0f) - x * ts[j] + log1pf(expf(-fabsf(x)));
            bc += 1.0f;
        }
        if (!g[j]) {
            svp += p; cv += 1.0f;
            if (!s[j]) { su += p; su2 += p * p; cu += 1.0f; }
        }
    }
    // width-32 group reduction: each 32-lane group = one query block
    #pragma unroll
    for (int off = 16; off > 0; off >>= 1) {
        svp += __shfl_down(svp, off, 32);
        cv  += __shfl_down(cv,  off, 32);
        su  += __shfl_down(su,  off, 32);
        su2 += __shfl_down(su2, off, 32);
        cu  += __shfl_down(cu,  off, 32);
        bs  += __shfl_down(bs,  off, 32);
        bc  += __shfl_down(bc,  off, 32);
    }
    if ((t & 31) == 0) {
        const int qb = blockIdx.x * 8 + (t >> 5);  // global query-block id
        ((float2*)(W + VC_OFF))[qb] = make_float2(svp, cv);
        ((float4*)(W + SU_OFF))[qb] = make_float4(su, su2, cu, 0.0f);
        ((float2*)(W + BC_OFF))[qb] = make_float2(bs, bc);
    }
    // zero the accumulators + ticket for kernel 2 (stream-ordered after us)
    if (blockIdx.x == 0 && t == 0) {
        #pragma unroll
        for (int i = 0; i < 34; ++i) W[P_OFF + i] = 0.0f;
        *((int*)(W + TICKET_OFF)) = 0;
    }
}

// Kernel 2: neighbor aggregation, slot-parallel. 256 blocks x 256 threads.
// Each 32-lane group handles 4 query blocks; one lane per k-slot, so the
// whole neighbor list is gathered in ONE parallel wave of float2 loads
// (coalesced kv_idx read, packed {Svp,Cv} gather), then a width-32
// butterfly reduce. Block covers 32 consecutive qblocks -> single batch b.
__global__ __launch_bounds__(256) void graph_kernel(
    const int* __restrict__ kv_idx, const int* __restrict__ kv_nb,
    float* __restrict__ W, float* __restrict__ out)
{
    const int t    = threadIdx.x;
    const int grp  = t >> 5;          // 0..7
    const int slot = t & 31;          // k-slot
    const int b    = blockIdx.x >> 4; // 16 blocks per batch (512/32)

    const float2* __restrict__ VC  = (const float2*)(W + VC_OFF);
    const float4* __restrict__ SU  = (const float4*)(W + SU_OFF);
    const float2* __restrict__ BCp = (const float2*)(W + BC_OFF);
    float* P    = W + P_OFF;
    int* ticket = (int*)(W + TICKET_OFF);
    const float2* __restrict__ VCb = VC + (b << 9);

    float loss_a = 0.f, nunc_a = 0.f, bs_a = 0.f, bc_a = 0.f;
    #pragma unroll
    for (int qq = 0; qq < 4; ++qq) {
        const int gb  = blockIdx.x * 32 + grp * 4 + qq;  // global qblock id
        const int knb = kv_nb[gb];
        float psum = 0.f, cnt = 0.f;
        if (slot < knb) {
            const int j = kv_idx[(size_t)gb * KK + slot]; // coalesced per group
            const float2 vc = VCb[j];                     // single 8B gather
            psum = vc.x; cnt = vc.y;
        }
        #pragma unroll
        for (int m = 16; m > 0; m >>= 1) {
            psum += __shfl_xor(psum, m, 32);
            cnt  += __shfl_xor(cnt,  m, 32);
        }
        if (slot == 0) {
            const float4 su  = SU[gb];
            const float2 bcv = BCp[gb];
            bs_a += bcv.x; bc_a += bcv.y;
            if (su.z > 0.0f && knb > 0 && cnt > 0.0f) {
                const float mm = psum / fmaxf(cnt, 1.0f);
                loss_a += su.y - 2.0f * mm * su.x + mm * mm * su.z;
                nunc_a += su.z;
            }
        }
    }

    __shared__ float s[8][4];
    if (slot == 0) {
        s[grp][0] = loss_a; s[grp][1] = nunc_a;
        s[grp][2] = bs_a;   s[grp][3] = bc_a;
    }
    __syncthreads();
    if (t == 0) {
        float l = 0.f, n = 0.f, bs = 0.f, bc = 0.f;
        #pragma unroll
        for (int g = 0; g < 8; ++g) {
            l += s[g][0]; n += s[g][1]; bs += s[g][2]; bc += s[g][3];
        }
        atomicAdd(&P[b * 2 + 0], l);
        atomicAdd(&P[b * 2 + 1], n);
        atomicAdd(&P[32], bs);
        atomicAdd(&P[33], bc);
        __threadfence();
        const int rank = atomicAdd(ticket, 1);
        if (rank == 255) {            // last block: finalize
            __threadfence();
            float gsum = 0.f, nval = 0.f;
            for (int b2 = 0; b2 < BB; ++b2) {
                const float lv = atomicAdd(&P[b2 * 2 + 0], 0.0f);  // coherent read
                const float nv = atomicAdd(&P[b2 * 2 + 1], 0.0f);
                if (nv > 0.0f) { gsum += lv / fmaxf(nv, 1.0f); nval += 1.0f; }
            }
            const float tbs = atomicAdd(&P[32], 0.0f);
            const float tbc = atomicAdd(&P[33], 0.0f);
            out[0] = tbs / fmaxf(tbc, 1.0f) + 0.3f * (gsum / fmaxf(nval, 1.0f));
        }
    }
}

extern "C" void kernel_launch(void* const* d_in, const int* in_sizes, int n_in,
                              void* d_out, int out_size, void* d_ws, size_t ws_size,
                              hipStream_t stream) {
    (void)in_sizes; (void)n_in; (void)out_size; (void)ws_size;
    const float* logits  = (const float*)d_in[0];
    const float* targets = (const float*)d_in[1];
    const unsigned char* supm = (const unsigned char*)d_in[2];
    const unsigned char* ignm = (const unsigned char*)d_in[3];
    const int* kv_idx = (const int*)d_in[4];
    const int* kv_nb  = (const int*)d_in[5];
    float* W   = (float*)d_ws;
    float* out = (float*)d_out;

    hipLaunchKernelGGL(stats_kernel, dim3(STATS_GRID), dim3(256), 0, stream,
                       logits, targets, supm, ignm, W);
    hipLaunchKernelGGL(graph_kernel, dim3(256), dim3(256), 0, stream,
                       kv_idx, kv_nb, W, out);
}